// Round 21
// baseline (323.931 us; speedup 1.0000x reference)
//
#include <hip/hip_runtime.h>
#include <hip/hip_fp16.h>

#define NN 100000   // nodes
#define NF 128      // input features
#define D  64       // hidden dim
#define NE 1600000  // edges
#define NZ 1000000  // hypergraph incidences
#define NH 50000    // hyperedges

#define NS (NN + NH + NN)          // 250000 concatenated id space
#define TOT (NE + 2 * NZ)          // 3600000 adjacency entries
#define NBUK 977                   // ceil(NS/256) buckets of 256 ids
#define NWG1 256                   // phase-1 workgroups
#define P2CAP 6144                 // bucket stride/capacity

typedef _Float16 half2v __attribute__((ext_vector_type(2)));

static __device__ __forceinline__ float waveReduceSum(float v) {
#pragma unroll
  for (int off = 32; off > 0; off >>= 1) v += __shfl_down(v, off);
  return v;
}

// Wave-uniform broadcast via readlane (VALU pipe, not ds_bpermute/LDS pipe).
static __device__ __forceinline__ float bcastf(float v, int l) {
  return __int_as_float(__builtin_amdgcn_readlane(__float_as_int(v), l));
}

#if __has_builtin(__builtin_amdgcn_fdot2)
static __device__ __forceinline__ float fdot2f(half2v a, half2v b, float c) {
  return __builtin_amdgcn_fdot2(a, b, c, false);
}
#else
static __device__ __forceinline__ float fdot2f(half2v a, half2v b, float c) {
  return fmaf((float)a.x, (float)b.x, fmaf((float)a.y, (float)b.y, c));
}
#endif

// ---------------------------------------------------------------------------
// sv[0:64)   u    = conv2_W @ v1          (v1 = lp_W[:64] @ head_W)
// sv[64:128) w2v  = cls_W  @ v2           (v2 = lp_W[64:] @ head_W)
// sv[128]    c_all= lp_b.head_W + head_b + conv2_b.v1 + cls_b.v2
// ---------------------------------------------------------------------------
__global__ void k_vecs(const float* __restrict__ conv2_W, const float* __restrict__ conv2_b,
                       const float* __restrict__ cls_W, const float* __restrict__ cls_b,
                       const float* __restrict__ lp_W, const float* __restrict__ lp_b,
                       const float* __restrict__ head_W, const float* __restrict__ head_b,
                       float* __restrict__ sv) {
  int t = threadIdx.x;  // 0..63, one wave
  __shared__ float v1[64], v2[64];
  float a1 = 0.f, a2 = 0.f;
  for (int c = 0; c < 64; ++c) {
    float hw = head_W[c];
    a1 = fmaf(lp_W[t * 64 + c], hw, a1);
    a2 = fmaf(lp_W[(64 + t) * 64 + c], hw, a2);
  }
  v1[t] = a1;
  v2[t] = a2;
  __syncthreads();
  float u = 0.f, w = 0.f;
  for (int c = 0; c < 64; ++c) {
    u = fmaf(conv2_W[t * 64 + c], v1[c], u);
    w = fmaf(cls_W[t * 64 + c], v2[c], w);
  }
  sv[t] = u;
  sv[64 + t] = w;
  float part = lp_b[t] * head_W[t] + conv2_b[t] * v1[t] + cls_b[t] * v2[t];
  part = waveReduceSum(part);
  if (t == 0) sv[128] = part + head_b[0];
}

// ---------------------------------------------------------------------------
// Pack weight matrices pairwise over k into fp16x2 tables.
// ---------------------------------------------------------------------------
__global__ void k_pack(const float* __restrict__ Wu, const float* __restrict__ W2,
                       const float* __restrict__ conv1_W, const float* __restrict__ lin_W,
                       const float* __restrict__ W1,
                       int* __restrict__ PK) {
  int t = blockIdx.x * 256 + threadIdx.x;
  if (t >= 16384) return;
  const float* srcm;
  int idx, roff = 0;
  if (t < 2048)       { srcm = Wu;      idx = t;          }
  else if (t < 4096)  { srcm = W2;      idx = t - 2048;  roff = 64; }
  else if (t < 8192)  { srcm = conv1_W; idx = t - 4096;  }
  else if (t < 12288) { srcm = lin_W;   idx = t - 8192;  }
  else if (t < 14336) { srcm = W1;      idx = t - 12288; }
  else                { srcm = W2;      idx = t - 14336; }
  int kk = idx >> 6, lane = idx & 63;
  half2v p;
  p.x = (_Float16)srcm[(roff + 2 * kk) * 64 + lane];
  p.y = (_Float16)srcm[(roff + 2 * kk + 1) * 64 + lane];
  PK[t] = __builtin_bit_cast(int, p);
}

// ---------------------------------------------------------------------------
// Fused dual K=128 GEMM over x (read ONCE as float2).  [R18-proven]
// ---------------------------------------------------------------------------
__global__ __launch_bounds__(256) void k_gemm128_dual(const float* __restrict__ x,
                                                      const int* __restrict__ C1P,
                                                      const int* __restrict__ LWP,
                                                      const float* __restrict__ lin_b,
                                                      const float* __restrict__ dinv,
                                                      __half* __restrict__ xw1p,
                                                      __half* __restrict__ h16, int nrows) {
  int lane = threadIdx.x & 63;
  int wave = threadIdx.x >> 6;
  int w1[64], w2[64];
#pragma unroll
  for (int k = 0; k < 64; ++k) {
    w1[k] = C1P[k * 64 + lane];
    w2[k] = LWP[k * 64 + lane];
  }
  float bb = lin_b[lane];
  int wid = blockIdx.x * 4 + wave;
  int nw = gridDim.x * 4;
  if (wid >= nrows) return;
  const float2* X2 = (const float2*)x;
  float2 v = X2[(size_t)wid * 64 + lane];
  for (int row = wid; row < nrows; row += nw) {
    int nrow = row + nw;
    float2 nv = make_float2(0.f, 0.f);
    if (nrow < nrows) nv = X2[(size_t)nrow * 64 + lane];
    half2v hv;
    hv.x = (_Float16)v.x;
    hv.y = (_Float16)v.y;
    int hvi = __builtin_bit_cast(int, hv);
    float a0 = 0.f, a1 = bb;
#pragma unroll
    for (int kk = 0; kk < 64; ++kk) {
      half2v xb = __builtin_bit_cast(half2v, __builtin_amdgcn_readlane(hvi, kk));
      a0 = fdot2f(xb, __builtin_bit_cast(half2v, w1[kk]), a0);
      a1 = fdot2f(xb, __builtin_bit_cast(half2v, w2[kk]), a1);
    }
    xw1p[(size_t)row * 64 + lane] = (__half)(a0 * dinv[row]);
    h16[(size_t)row * 64 + lane] = (__half)fmaxf(a1, 0.f);
    v = nv;
  }
}

// ---------------------------------------------------------------------------
// Fused dual K=64 GEMM over h (fp16, read once).  [R18-proven]
// ---------------------------------------------------------------------------
__global__ __launch_bounds__(256) void k_gemm_dual(const __half* __restrict__ in,
                                                   const int* __restrict__ W1P,
                                                   const float* __restrict__ b1,
                                                   const int* __restrict__ W2AP,
                                                   __half* __restrict__ Cout,
                                                   __half* __restrict__ Aout, int nrows) {
  int lane = threadIdx.x & 63;
  int wave = threadIdx.x >> 6;
  int w1[32], w2[32];
#pragma unroll
  for (int k = 0; k < 32; ++k) {
    w1[k] = W1P[k * 64 + lane];
    w2[k] = W2AP[k * 64 + lane];
  }
  float bb = b1[lane];
  int wid = blockIdx.x * 4 + wave;
  int nw = gridDim.x * 4;
  if (wid >= nrows) return;
  const half2v* IN2 = (const half2v*)in;
  int c32 = lane & 31;
  half2v v = IN2[(size_t)wid * 32 + c32];
  for (int row = wid; row < nrows; row += nw) {
    int nrow = row + nw;
    half2v nv = {(_Float16)0.f, (_Float16)0.f};
    if (nrow < nrows) nv = IN2[(size_t)nrow * 32 + c32];
    int hvi = __builtin_bit_cast(int, v);
    float accC = bb, accA = 0.f;
#pragma unroll
    for (int kk = 0; kk < 32; ++kk) {
      half2v xb = __builtin_bit_cast(half2v, __builtin_amdgcn_readlane(hvi, kk));
      accC = fdot2f(xb, __builtin_bit_cast(half2v, w1[kk]), accC);
      accA = fdot2f(xb, __builtin_bit_cast(half2v, w2[kk]), accA);
    }
    Cout[(size_t)row * 64 + lane] = (__half)accC;
    Aout[(size_t)row * 64 + lane] = (__half)accA;
    v = nv;
  }
}

// ---------------------------------------------------------------------------
// CSR build (no global scan): fixed-stride buckets at b*P2CAP.
// ---------------------------------------------------------------------------
__global__ __launch_bounds__(1024) void k_phase1(const int* __restrict__ src,
                                                 const int* __restrict__ dst,
                                                 const int* __restrict__ he,
                                                 const int* __restrict__ hv,
                                                 int* __restrict__ gcur,
                                                 int* __restrict__ adj) {
  __shared__ int cnt[NBUK], base[NBUK], cur[NBUK];
  int tid = threadIdx.x;
  for (int b = tid; b < NBUK; b += 1024) { cnt[b] = 0; cur[b] = 0; }
  __syncthreads();
  int per = (TOT + NWG1 - 1) / NWG1;
  int s0 = blockIdx.x * per;
  int s1 = s0 + per; if (s1 > TOT) s1 = TOT;
  for (int j = s0 + tid; j < s1; j += 1024) {
    int id;
    if (j < NE) id = dst[j];
    else if (j < NE + NZ) id = NN + he[j - NE];
    else id = NN + NH + hv[j - NE - NZ];
    atomicAdd(&cnt[id >> 8], 1);
  }
  __syncthreads();
  for (int b = tid; b < NBUK; b += 1024) {
    int c = cnt[b];
    if (c) base[b] = b * P2CAP + atomicAdd(&gcur[b], c);
  }
  __syncthreads();
  for (int j = s0 + tid; j < s1; j += 1024) {
    int id, val;
    if (j < NE)           { id = dst[j];                val = src[j]; }
    else if (j < NE + NZ) { id = NN + he[j - NE];       val = hv[j - NE]; }
    else                  { id = NN + NH + hv[j - NE - NZ]; val = he[j - NE - NZ]; }
    int b = id >> 8;
    int slot = base[b] + atomicAdd(&cur[b], 1);
    adj[slot] = ((id & 255) << 17) | val;   // val < 131072
  }
}

__global__ __launch_bounds__(256) void k_phase2(const int* __restrict__ gcur,
                                                int* __restrict__ adj,
                                                int* __restrict__ offb,
                                                int* __restrict__ offe) {
  __shared__ int ent[P2CAP];
  __shared__ int hist[256];
  int b = blockIdx.x, tid = threadIdx.x;
  int s = b * P2CAP;
  int n = gcur[b];
  if (n > P2CAP) n = P2CAP;  // safety; cannot trigger on this dataset
  hist[tid] = 0;
  __syncthreads();
  for (int k = tid; k < n; k += 256) {
    int v = adj[s + k];
    ent[k] = v;
    atomicAdd(&hist[v >> 17], 1);
  }
  __syncthreads();
  int c = hist[tid];
#pragma unroll
  for (int d = 1; d < 256; d <<= 1) {
    int x = (tid >= d) ? hist[tid - d] : 0;
    __syncthreads();
    hist[tid] += x;
    __syncthreads();
  }
  int excl = hist[tid] - c;
  hist[tid] = excl;
  int gid = (b << 8) + tid;
  if (gid < NS) {
    offb[gid] = s + excl;
    offe[gid] = s + excl + c;
  }
  __syncthreads();
  for (int k = tid; k < n; k += 256) {
    int v = ent[k];
    int pos = atomicAdd(&hist[v >> 17], 1);
    adj[s + pos] = v & 0x1FFFF;   // store bare value
  }
}

__global__ void k_dinv(const int* __restrict__ offb, const int* __restrict__ offe,
                       float* __restrict__ dinv) {
  int i = blockIdx.x * 256 + threadIdx.x;
  if (i < NN) dinv[i] = rsqrtf((float)(offe[i] - offb[i] + 1));  // +1 self-loop
}

// ---------------------------------------------------------------------------
// Packed gathers. 64 lanes = 32 col-pairs (c) x 2 element-slots (eo).
// GATHER_ONE: single range, chunked (PKBODY sees r_[q], b2, ok).
// GATHER_PAIR: first 64-chunk of two ranges interleaved (16 loads in flight).
// ---------------------------------------------------------------------------
#define GATHER_ONE(ROWS2, BEG, END, AX, AY, PKBODY)                     \
  for (int j0 = (BEG); j0 < (END); j0 += 64) {                          \
    int m = (END) - j0; if (m > 64) m = 64;                             \
    int a = (lane < m) ? adj[j0 + lane] : 0;                            \
    int cl = m - 1;                                                     \
    for (int k = 0; k < m; k += 16) {                                   \
      half2v r_[8];                                                     \
      _Pragma("unroll")                                                 \
      for (int q = 0; q < 8; ++q) {                                     \
        int kk = k + 2 * q + eo; kk = (kk < cl) ? kk : cl;              \
        r_[q] = ROWS2[(size_t)__shfl(a, kk) * 32 + c];                  \
      }                                                                 \
      half2v b2 = hz;                                                   \
      _Pragma("unroll")                                                 \
      for (int q = 0; q < 8; ++q) {                                     \
        bool ok = (k + 2 * q + eo) < m;                                 \
        PKBODY                                                          \
      }                                                                 \
      AX += (float)b2.x; AY += (float)b2.y;                             \
    }                                                                   \
  }

#define GATHER_PAIR(ROWS2, B0v, E0v, B1v, E1v, PK0, PK1)                \
  {                                                                     \
    int mA = (E0v) - (B0v), mB = (E1v) - (B1v);                         \
    int aA = (lane < mA) ? adj[(B0v) + lane] : 0;                       \
    int aB = (lane < mB) ? adj[(B1v) + lane] : 0;                       \
    if (mA > 64) mA = 64;                                               \
    if (mB > 64) mB = 64;                                               \
    int clA = (mA > 0) ? mA - 1 : 0;                                    \
    int clB = (mB > 0) ? mB - 1 : 0;                                    \
    int mm = (mA > mB) ? mA : mB;                                       \
    for (int k = 0; k < mm; k += 16) {                                  \
      half2v r0_[8], r1_[8];                                            \
      _Pragma("unroll")                                                 \
      for (int q = 0; q < 8; ++q) {                                     \
        int kk = k + 2 * q + eo; int kc = (kk < clA) ? kk : clA;        \
        r0_[q] = ROWS2[(size_t)__shfl(aA, kc) * 32 + c];                \
      }                                                                 \
      _Pragma("unroll")                                                 \
      for (int q = 0; q < 8; ++q) {                                     \
        int kk = k + 2 * q + eo; int kc = (kk < clB) ? kk : clB;        \
        r1_[q] = ROWS2[(size_t)__shfl(aB, kc) * 32 + c];                \
      }                                                                 \
      half2v b20 = hz, b21 = hz;                                        \
      _Pragma("unroll")                                                 \
      for (int q = 0; q < 8; ++q) { bool ok = (k + 2 * q + eo) < mA; PK0 } \
      _Pragma("unroll")                                                 \
      for (int q = 0; q < 8; ++q) { bool ok = (k + 2 * q + eo) < mB; PK1 } \
      ax0 += (float)b20.x; ay0 += (float)b20.y;                         \
      ax1 += (float)b21.x; ay1 += (float)b21.y;                         \
    }                                                                   \
  }

// ---------------------------------------------------------------------------
// conv1 gather, 2 nodes per wave (paired, interleaved loads).  [R19-proven]
// ---------------------------------------------------------------------------
__global__ __launch_bounds__(256) void k_gcn1_gather(const int* __restrict__ offb,
                                                     const int* __restrict__ offe,
                                                     const int* __restrict__ adj,
                                                     const __half* __restrict__ xw1p,
                                                     const float* __restrict__ dinv,
                                                     const float* __restrict__ conv1_b,
                                                     const float* __restrict__ sv,
                                                     float* __restrict__ tp) {
  int w = blockIdx.x * 4 + (threadIdx.x >> 6);
  int i0 = 2 * w, i1 = 2 * w + 1;
  if (i0 >= NN) return;
  int lane = threadIdx.x & 63;
  int c = lane & 31, eo = lane >> 5;
  const half2v hz = {(_Float16)0.f, (_Float16)0.f};
  const half2v* X2 = (const half2v*)xw1p;
  int B0 = offb[i0], E0 = offe[i0];
  int B1 = offb[i1], E1 = offe[i1];
  float ax0 = 0.f, ay0 = 0.f, ax1 = 0.f, ay1 = 0.f;
  GATHER_PAIR(X2, B0, E0, B1, E1,
              { b20 += ok ? r0_[q] : hz; },
              { b21 += ok ? r1_[q] : hz; })
  if (E0 - B0 > 64) GATHER_ONE(X2, B0 + 64, E0, ax0, ay0, { b2 += ok ? r_[q] : hz; })
  if (E1 - B1 > 64) GATHER_ONE(X2, B1 + 64, E1, ax1, ay1, { b2 += ok ? r_[q] : hz; })
  ax0 += __shfl_xor(ax0, 32); ay0 += __shfl_xor(ay0, 32);
  ax1 += __shfl_xor(ax1, 32); ay1 += __shfl_xor(ay1, 32);
  float cb0 = conv1_b[2 * c], cb1 = conv1_b[2 * c + 1];
  float u0 = sv[2 * c], u1 = sv[2 * c + 1];
  {
    float di = dinv[i0];
    half2v self2 = X2[(size_t)i0 * 32 + c];
    float r0 = fmaxf(fmaf(ax0 + (float)self2.x, di, cb0), 0.f);
    float r1 = fmaxf(fmaf(ay0 + (float)self2.y, di, cb1), 0.f);
    float p = r0 * u0 + r1 * u1;
    if (eo) p = 0.f;
    p = waveReduceSum(p);
    if (lane == 0) tp[i0] = p * di;
  }
  {
    float di = dinv[i1];
    half2v self2 = X2[(size_t)i1 * 32 + c];
    float r0 = fmaxf(fmaf(ax1 + (float)self2.x, di, cb0), 0.f);
    float r1 = fmaxf(fmaf(ay1 + (float)self2.y, di, cb1), 0.f);
    float p = r0 * u0 + r1 * u1;
    if (eo) p = 0.f;
    p = waveReduceSum(p);
    if (lane == 0) tp[i1] = p * di;
  }
}

// ---------------------------------------------------------------------------
// Xe gather + batched matvec. 4 hyperedges/wave (2 pairs), grid 3125.
// LDS-FREE: hpre packed directly into hvp registers (lanes 0..31 feed
// readlane; NH = 3125*4*4 exactly, so loops fully unrolled, static indices).
// ---------------------------------------------------------------------------
__global__ __launch_bounds__(256) void k_xe_gather(const int* __restrict__ offb,
                                                   const int* __restrict__ offe,
                                                   const int* __restrict__ adj,
                                                   const __half* __restrict__ C,
                                                   const int* __restrict__ W2P,
                                                   const float* __restrict__ b2bias,
                                                   __half* __restrict__ B) {
  int lane = threadIdx.x & 63, wv = threadIdx.x >> 6;
  int c = lane & 31, eo = lane >> 5;
  const half2v hz = {(_Float16)0.f, (_Float16)0.f};
  const half2v* C2 = (const half2v*)C;
  int base = (blockIdx.x * 4 + wv) * 4;
  int hvp[4];
#pragma unroll
  for (int np = 0; np < 2; ++np) {
    int e0 = base + 2 * np, e1 = e0 + 1;
    int B0 = offb[NN + e0], E0 = offe[NN + e0];
    int B1 = offb[NN + e1], E1 = offe[NN + e1];
    float ax0 = 0.f, ay0 = 0.f, ax1 = 0.f, ay1 = 0.f;
    GATHER_PAIR(C2, B0, E0, B1, E1,
                { b20 += ok ? r0_[q] : hz; },
                { b21 += ok ? r1_[q] : hz; })
    if (E0 - B0 > 64) GATHER_ONE(C2, B0 + 64, E0, ax0, ay0, { b2 += ok ? r_[q] : hz; })
    if (E1 - B1 > 64) GATHER_ONE(C2, B1 + 64, E1, ax1, ay1, { b2 += ok ? r_[q] : hz; })
    ax0 += __shfl_xor(ax0, 32); ay0 += __shfl_xor(ay0, 32);
    ax1 += __shfl_xor(ax1, 32); ay1 += __shfl_xor(ay1, 32);
    float sc0 = 1.0f / fmaxf((float)(E0 - B0), 1.f);
    float sc1 = 1.0f / fmaxf((float)(E1 - B1), 1.f);
    half2v p0, p1;
    p0.x = (_Float16)(ax0 * sc0); p0.y = (_Float16)(ay0 * sc0);
    p1.x = (_Float16)(ax1 * sc1); p1.y = (_Float16)(ay1 * sc1);
    hvp[2 * np] = __builtin_bit_cast(int, p0);
    hvp[2 * np + 1] = __builtin_bit_cast(int, p1);
  }
  float bb = b2bias[lane];
  float acc[4];
#pragma unroll
  for (int n = 0; n < 4; ++n) acc[n] = bb;
  for (int kk = 0; kk < 32; ++kk) {
    half2v wp = __builtin_bit_cast(half2v, W2P[kk * 64 + lane]);
#pragma unroll
    for (int n = 0; n < 4; ++n) {
      half2v hb = __builtin_bit_cast(half2v, __builtin_amdgcn_readlane(hvp[n], kk));
      acc[n] = fdot2f(hb, wp, acc[n]);
    }
  }
#pragma unroll
  for (int n = 0; n < 4; ++n)
    B[(size_t)(base + n) * 64 + lane] = (__half)acc[n];
}

// ---------------------------------------------------------------------------
// Final fused kernel. 8 nodes/wave sequential, LDS-FREE:
// hpre packed into hvp registers (valid in all lanes after xor-combine);
// gcn2 scalar kept in sreg (lane 0's copy consumed). NN = 3125*4*8 exactly.
// ---------------------------------------------------------------------------
__global__ __launch_bounds__(256) void k_final(const int* __restrict__ offb,
                                               const int* __restrict__ offe,
                                               const int* __restrict__ adj,
                                               const __half* __restrict__ A,
                                               const __half* __restrict__ B,
                                               const __half* __restrict__ h,
                                               const float* __restrict__ tp,
                                               const float* __restrict__ dinv,
                                               const int* __restrict__ WUP,
                                               const float* __restrict__ bu,
                                               const float* __restrict__ sv,
                                               float* __restrict__ out) {
  int lane = threadIdx.x & 63, wv = threadIdx.x >> 6;
  int c = lane & 31, eo = lane >> 5;
  const half2v hz = {(_Float16)0.f, (_Float16)0.f};
  const half2v* A2 = (const half2v*)A;
  const half2v* B2 = (const half2v*)B;
  const half2v* H2 = (const half2v*)h;
  int base = (blockIdx.x * 4 + wv) * 8;
  float c_all = sv[128];
  int hvp[8];
  float sreg[8];
#pragma unroll
  for (int n = 0; n < 8; ++n) {
    int i = base + n;
    half2v av2 = A2[(size_t)i * 32 + c];
    int beg = offb[NN + NH + i], end = offe[NN + NH + i];
    float ax = 0.f, ay = 0.f;
    GATHER_ONE(B2, beg, end, ax, ay, {
      half2v s = av2 + r_[q];
      s = __builtin_elementwise_max(s, hz);
      b2 += ok ? s : hz;
    })
    ax += __shfl_xor(ax, 32);
    ay += __shfl_xor(ay, 32);
    float sc = 0.5f / fmaxf((float)(end - beg), 1.f);
    half2v h2 = H2[(size_t)i * 32 + c];
    half2v pk;
    pk.x = (_Float16)(ax * sc + 0.5f * (float)h2.x);
    pk.y = (_Float16)(ay * sc + 0.5f * (float)h2.y);
    hvp[n] = __builtin_bit_cast(int, pk);
    // gcn2 scalar gather over dst-CSR (all 64 lanes)
    float di = dinv[i];
    int db = offb[i], de = offe[i];
    float g = 0.f;
    for (int j = db + lane; j < de; j += 64) g += tp[adj[j]];
    float gr = waveReduceSum(g);
    sreg[n] = gr * di + tp[i] * di + c_all;   // valid in lane 0
  }
  float bb = bu[lane];
  float w2v = sv[64 + lane];
  float acc[8];
#pragma unroll
  for (int n = 0; n < 8; ++n) acc[n] = bb;
  for (int kk = 0; kk < 32; ++kk) {
    half2v wp = __builtin_bit_cast(half2v, WUP[kk * 64 + lane]);
#pragma unroll
    for (int n = 0; n < 8; ++n) {
      half2v hb = __builtin_bit_cast(half2v, __builtin_amdgcn_readlane(hvp[n], kk));
      acc[n] = fdot2f(hb, wp, acc[n]);
    }
  }
#pragma unroll
  for (int n = 0; n < 8; ++n) {
    float part = fmaxf(acc[n], 0.f) * w2v;
    float tot = waveReduceSum(part);
    if (lane == 0) out[base + n] = tot + sreg[n];
  }
}

// ---------------------------------------------------------------------------
extern "C" void kernel_launch(void* const* d_in, const int* in_sizes, int n_in,
                              void* d_out, int out_size, void* d_ws, size_t ws_size,
                              hipStream_t stream) {
  (void)in_sizes; (void)n_in; (void)out_size; (void)ws_size;
  const float* x       = (const float*)d_in[0];
  const int*   ei      = (const int*)d_in[1];
  const int*   hv      = (const int*)d_in[2];
  const int*   he      = (const int*)d_in[3];
  const float* conv1_W = (const float*)d_in[5];
  const float* conv1_b = (const float*)d_in[6];
  const float* conv2_W = (const float*)d_in[7];
  const float* conv2_b = (const float*)d_in[8];
  const float* lin_W   = (const float*)d_in[9];
  const float* lin_b   = (const float*)d_in[10];
  const float* W1      = (const float*)d_in[11];
  const float* b1      = (const float*)d_in[12];
  const float* W2      = (const float*)d_in[13];
  const float* b2      = (const float*)d_in[14];
  const float* Wu      = (const float*)d_in[15];
  const float* bu      = (const float*)d_in[16];
  const float* cls_W   = (const float*)d_in[17];
  const float* cls_b   = (const float*)d_in[18];
  const float* lp_W    = (const float*)d_in[19];
  const float* lp_b    = (const float*)d_in[20];
  const float* head_W  = (const float*)d_in[21];
  const float* head_b  = (const float*)d_in[22];
  const int* src = ei;
  const int* dst = ei + NE;
  float* out = (float*)d_out;

  // workspace layout
  __half* H16  = (__half*)d_ws;                         // NN*64 fp16  h
  __half* PH   = H16 + (size_t)NN * 64;                 // NN*64 fp16  xw1' then C
  __half* QH   = PH + (size_t)NN * 64;                  // NN*64 fp16  A
  __half* XEH  = QH + (size_t)NN * 64;                  // NH*64 fp16  B
  float* DINV  = (float*)(XEH + (size_t)NH * 64);       // NN
  float* TP    = DINV + NN;                 // NN   t' = t*dinv
  float* SV    = TP + NN;                   // 192
  int* PK      = (int*)(SV + 192);          // 16384 packed fp16x2 weight tables
  int* WUP     = PK;                        //  [0,2048)
  int* W2P     = PK + 2048;                 //  [2048,4096)
  int* C1P     = PK + 4096;                 //  [4096,8192)
  int* LWP     = PK + 8192;                 //  [8192,12288)
  int* W1P     = PK + 12288;                //  [12288,14336)
  int* W2AP    = PK + 14336;                //  [14336,16384)
  int* GCUR    = PK + 16384;                // NBUK
  int* OFFB    = GCUR + NBUK;               // NS
  int* OFFE    = OFFB + NS;                 // NS
  int* ADJ     = OFFE + NS;                 // NBUK*P2CAP (24 MB)

  hipMemsetAsync(GCUR, 0, NBUK * 4, stream);

  k_vecs<<<1, 64, 0, stream>>>(conv2_W, conv2_b, cls_W, cls_b, lp_W, lp_b, head_W, head_b, SV);
  k_pack<<<64, 256, 0, stream>>>(Wu, W2, conv1_W, lin_W, W1, PK);

  // CSR build (strided buckets; no global scan pass)
  k_phase1<<<NWG1, 1024, 0, stream>>>(src, dst, he, hv, GCUR, ADJ);
  k_phase2<<<NBUK, 256, 0, stream>>>(GCUR, ADJ, OFFB, OFFE);
  k_dinv<<<(NN + 255) / 256, 256, 0, stream>>>(OFFB, OFFE, DINV);

  // dense: xw1' and h in ONE pass over x
  k_gemm128_dual<<<2048, 256, 0, stream>>>(x, C1P, LWP, lin_b, DINV, PH, H16, NN);

  // GCN branch collapsed to t' (2 nodes/wave -> 12500 blocks)
  k_gcn1_gather<<<12500, 256, 0, stream>>>(OFFB, OFFE, ADJ, PH, DINV, conv1_b, SV, TP);

  // hyper branch dense parts fused: C = h@W1+b1 (PH), A = h@W2[:64] (QH)
  k_gemm_dual<<<2048, 256, 0, stream>>>(H16, W1P, b1, W2AP, PH, QH, NN);

  // 4 hyperedges per wave -> 3125 blocks (LDS-free)
  k_xe_gather<<<3125, 256, 0, stream>>>(OFFB, OFFE, ADJ, PH, W2P, b2, XEH);

  // 8 nodes per wave -> 3125 blocks (LDS-free)
  k_final<<<3125, 256, 0, stream>>>(OFFB, OFFE, ADJ, QH, XEH, H16, TP, DINV, WUP, bu, SV, out);
}

// Round 22
// 289.745 us; speedup vs baseline: 1.1180x; 1.1180x over previous
//
#include <hip/hip_runtime.h>
#include <hip/hip_fp16.h>

#define NN 100000   // nodes
#define NF 128      // input features
#define D  64       // hidden dim
#define NE 1600000  // edges
#define NZ 1000000  // hypergraph incidences
#define NH 50000    // hyperedges

#define NS (NN + NH + NN)          // 250000 concatenated id space
#define TOT (NE + 2 * NZ)          // 3600000 adjacency entries
#define NBUK 977                   // ceil(NS/256) buckets of 256 ids
#define NWG1 256                   // phase-1 workgroups
#define P2CAP 6144                 // bucket stride/capacity

typedef _Float16 half2v __attribute__((ext_vector_type(2)));

static __device__ __forceinline__ float waveReduceSum(float v) {
#pragma unroll
  for (int off = 32; off > 0; off >>= 1) v += __shfl_down(v, off);
  return v;
}

// Wave-uniform broadcast via readlane (VALU pipe, not ds_bpermute/LDS pipe).
static __device__ __forceinline__ float bcastf(float v, int l) {
  return __int_as_float(__builtin_amdgcn_readlane(__float_as_int(v), l));
}

#if __has_builtin(__builtin_amdgcn_fdot2)
static __device__ __forceinline__ float fdot2f(half2v a, half2v b, float c) {
  return __builtin_amdgcn_fdot2(a, b, c, false);
}
#else
static __device__ __forceinline__ float fdot2f(half2v a, half2v b, float c) {
  return fmaf((float)a.x, (float)b.x, fmaf((float)a.y, (float)b.y, c));
}
#endif

// ---------------------------------------------------------------------------
// sv[0:64)   u    = conv2_W @ v1          (v1 = lp_W[:64] @ head_W)
// sv[64:128) w2v  = cls_W  @ v2           (v2 = lp_W[64:] @ head_W)
// sv[128]    c_all= lp_b.head_W + head_b + conv2_b.v1 + cls_b.v2
// ---------------------------------------------------------------------------
__global__ void k_vecs(const float* __restrict__ conv2_W, const float* __restrict__ conv2_b,
                       const float* __restrict__ cls_W, const float* __restrict__ cls_b,
                       const float* __restrict__ lp_W, const float* __restrict__ lp_b,
                       const float* __restrict__ head_W, const float* __restrict__ head_b,
                       float* __restrict__ sv) {
  int t = threadIdx.x;  // 0..63, one wave
  __shared__ float v1[64], v2[64];
  float a1 = 0.f, a2 = 0.f;
  for (int c = 0; c < 64; ++c) {
    float hw = head_W[c];
    a1 = fmaf(lp_W[t * 64 + c], hw, a1);
    a2 = fmaf(lp_W[(64 + t) * 64 + c], hw, a2);
  }
  v1[t] = a1;
  v2[t] = a2;
  __syncthreads();
  float u = 0.f, w = 0.f;
  for (int c = 0; c < 64; ++c) {
    u = fmaf(conv2_W[t * 64 + c], v1[c], u);
    w = fmaf(cls_W[t * 64 + c], v2[c], w);
  }
  sv[t] = u;
  sv[64 + t] = w;
  float part = lp_b[t] * head_W[t] + conv2_b[t] * v1[t] + cls_b[t] * v2[t];
  part = waveReduceSum(part);
  if (t == 0) sv[128] = part + head_b[0];
}

// ---------------------------------------------------------------------------
// Pack weight matrices pairwise over k into fp16x2 tables.
// ---------------------------------------------------------------------------
__global__ void k_pack(const float* __restrict__ Wu, const float* __restrict__ W2,
                       const float* __restrict__ conv1_W, const float* __restrict__ lin_W,
                       const float* __restrict__ W1,
                       int* __restrict__ PK) {
  int t = blockIdx.x * 256 + threadIdx.x;
  if (t >= 16384) return;
  const float* srcm;
  int idx, roff = 0;
  if (t < 2048)       { srcm = Wu;      idx = t;          }
  else if (t < 4096)  { srcm = W2;      idx = t - 2048;  roff = 64; }
  else if (t < 8192)  { srcm = conv1_W; idx = t - 4096;  }
  else if (t < 12288) { srcm = lin_W;   idx = t - 8192;  }
  else if (t < 14336) { srcm = W1;      idx = t - 12288; }
  else                { srcm = W2;      idx = t - 14336; }
  int kk = idx >> 6, lane = idx & 63;
  half2v p;
  p.x = (_Float16)srcm[(roff + 2 * kk) * 64 + lane];
  p.y = (_Float16)srcm[(roff + 2 * kk + 1) * 64 + lane];
  PK[t] = __builtin_bit_cast(int, p);
}

// ---------------------------------------------------------------------------
// Fused dual K=128 GEMM over x (read ONCE as float2).  [R18-proven]
// ---------------------------------------------------------------------------
__global__ __launch_bounds__(256) void k_gemm128_dual(const float* __restrict__ x,
                                                      const int* __restrict__ C1P,
                                                      const int* __restrict__ LWP,
                                                      const float* __restrict__ lin_b,
                                                      const float* __restrict__ dinv,
                                                      __half* __restrict__ xw1p,
                                                      __half* __restrict__ h16, int nrows) {
  int lane = threadIdx.x & 63;
  int wave = threadIdx.x >> 6;
  int w1[64], w2[64];
#pragma unroll
  for (int k = 0; k < 64; ++k) {
    w1[k] = C1P[k * 64 + lane];
    w2[k] = LWP[k * 64 + lane];
  }
  float bb = lin_b[lane];
  int wid = blockIdx.x * 4 + wave;
  int nw = gridDim.x * 4;
  if (wid >= nrows) return;
  const float2* X2 = (const float2*)x;
  float2 v = X2[(size_t)wid * 64 + lane];
  for (int row = wid; row < nrows; row += nw) {
    int nrow = row + nw;
    float2 nv = make_float2(0.f, 0.f);
    if (nrow < nrows) nv = X2[(size_t)nrow * 64 + lane];
    half2v hv;
    hv.x = (_Float16)v.x;
    hv.y = (_Float16)v.y;
    int hvi = __builtin_bit_cast(int, hv);
    float a0 = 0.f, a1 = bb;
#pragma unroll
    for (int kk = 0; kk < 64; ++kk) {
      half2v xb = __builtin_bit_cast(half2v, __builtin_amdgcn_readlane(hvi, kk));
      a0 = fdot2f(xb, __builtin_bit_cast(half2v, w1[kk]), a0);
      a1 = fdot2f(xb, __builtin_bit_cast(half2v, w2[kk]), a1);
    }
    xw1p[(size_t)row * 64 + lane] = (__half)(a0 * dinv[row]);
    h16[(size_t)row * 64 + lane] = (__half)fmaxf(a1, 0.f);
    v = nv;
  }
}

// ---------------------------------------------------------------------------
// Fused dual K=64 GEMM over h (fp16, read once).  [R18-proven]
// ---------------------------------------------------------------------------
__global__ __launch_bounds__(256) void k_gemm_dual(const __half* __restrict__ in,
                                                   const int* __restrict__ W1P,
                                                   const float* __restrict__ b1,
                                                   const int* __restrict__ W2AP,
                                                   __half* __restrict__ Cout,
                                                   __half* __restrict__ Aout, int nrows) {
  int lane = threadIdx.x & 63;
  int wave = threadIdx.x >> 6;
  int w1[32], w2[32];
#pragma unroll
  for (int k = 0; k < 32; ++k) {
    w1[k] = W1P[k * 64 + lane];
    w2[k] = W2AP[k * 64 + lane];
  }
  float bb = b1[lane];
  int wid = blockIdx.x * 4 + wave;
  int nw = gridDim.x * 4;
  if (wid >= nrows) return;
  const half2v* IN2 = (const half2v*)in;
  int c32 = lane & 31;
  half2v v = IN2[(size_t)wid * 32 + c32];
  for (int row = wid; row < nrows; row += nw) {
    int nrow = row + nw;
    half2v nv = {(_Float16)0.f, (_Float16)0.f};
    if (nrow < nrows) nv = IN2[(size_t)nrow * 32 + c32];
    int hvi = __builtin_bit_cast(int, v);
    float accC = bb, accA = 0.f;
#pragma unroll
    for (int kk = 0; kk < 32; ++kk) {
      half2v xb = __builtin_bit_cast(half2v, __builtin_amdgcn_readlane(hvi, kk));
      accC = fdot2f(xb, __builtin_bit_cast(half2v, w1[kk]), accC);
      accA = fdot2f(xb, __builtin_bit_cast(half2v, w2[kk]), accA);
    }
    Cout[(size_t)row * 64 + lane] = (__half)accC;
    Aout[(size_t)row * 64 + lane] = (__half)accA;
    v = nv;
  }
}

// ---------------------------------------------------------------------------
// CSR build (no global scan): fixed-stride buckets at b*P2CAP.
// ---------------------------------------------------------------------------
__global__ __launch_bounds__(1024) void k_phase1(const int* __restrict__ src,
                                                 const int* __restrict__ dst,
                                                 const int* __restrict__ he,
                                                 const int* __restrict__ hv,
                                                 int* __restrict__ gcur,
                                                 int* __restrict__ adj) {
  __shared__ int cnt[NBUK], base[NBUK], cur[NBUK];
  int tid = threadIdx.x;
  for (int b = tid; b < NBUK; b += 1024) { cnt[b] = 0; cur[b] = 0; }
  __syncthreads();
  int per = (TOT + NWG1 - 1) / NWG1;
  int s0 = blockIdx.x * per;
  int s1 = s0 + per; if (s1 > TOT) s1 = TOT;
  for (int j = s0 + tid; j < s1; j += 1024) {
    int id;
    if (j < NE) id = dst[j];
    else if (j < NE + NZ) id = NN + he[j - NE];
    else id = NN + NH + hv[j - NE - NZ];
    atomicAdd(&cnt[id >> 8], 1);
  }
  __syncthreads();
  for (int b = tid; b < NBUK; b += 1024) {
    int c = cnt[b];
    if (c) base[b] = b * P2CAP + atomicAdd(&gcur[b], c);
  }
  __syncthreads();
  for (int j = s0 + tid; j < s1; j += 1024) {
    int id, val;
    if (j < NE)           { id = dst[j];                val = src[j]; }
    else if (j < NE + NZ) { id = NN + he[j - NE];       val = hv[j - NE]; }
    else                  { id = NN + NH + hv[j - NE - NZ]; val = he[j - NE - NZ]; }
    int b = id >> 8;
    int slot = base[b] + atomicAdd(&cur[b], 1);
    adj[slot] = ((id & 255) << 17) | val;   // val < 131072
  }
}

__global__ __launch_bounds__(256) void k_phase2(const int* __restrict__ gcur,
                                                int* __restrict__ adj,
                                                int* __restrict__ offb,
                                                int* __restrict__ offe) {
  __shared__ int ent[P2CAP];
  __shared__ int hist[256];
  int b = blockIdx.x, tid = threadIdx.x;
  int s = b * P2CAP;
  int n = gcur[b];
  if (n > P2CAP) n = P2CAP;  // safety; cannot trigger on this dataset
  hist[tid] = 0;
  __syncthreads();
  for (int k = tid; k < n; k += 256) {
    int v = adj[s + k];
    ent[k] = v;
    atomicAdd(&hist[v >> 17], 1);
  }
  __syncthreads();
  int c = hist[tid];
#pragma unroll
  for (int d = 1; d < 256; d <<= 1) {
    int x = (tid >= d) ? hist[tid - d] : 0;
    __syncthreads();
    hist[tid] += x;
    __syncthreads();
  }
  int excl = hist[tid] - c;
  hist[tid] = excl;
  int gid = (b << 8) + tid;
  if (gid < NS) {
    offb[gid] = s + excl;
    offe[gid] = s + excl + c;
  }
  __syncthreads();
  for (int k = tid; k < n; k += 256) {
    int v = ent[k];
    int pos = atomicAdd(&hist[v >> 17], 1);
    adj[s + pos] = v & 0x1FFFF;   // store bare value
  }
}

__global__ void k_dinv(const int* __restrict__ offb, const int* __restrict__ offe,
                       float* __restrict__ dinv) {
  int i = blockIdx.x * 256 + threadIdx.x;
  if (i < NN) dinv[i] = rsqrtf((float)(offe[i] - offb[i] + 1));  // +1 self-loop
}

// ---------------------------------------------------------------------------
// Packed gathers. 64 lanes = 32 col-pairs (c) x 2 element-slots (eo).
// GATHER_ONE: single range, chunked (PKBODY sees r_[q], b2, ok).
// GATHER_PAIR: first 64-chunk of two ranges interleaved (16 loads in flight).
// ---------------------------------------------------------------------------
#define GATHER_ONE(ROWS2, BEG, END, AX, AY, PKBODY)                     \
  for (int j0 = (BEG); j0 < (END); j0 += 64) {                          \
    int m = (END) - j0; if (m > 64) m = 64;                             \
    int a = (lane < m) ? adj[j0 + lane] : 0;                            \
    int cl = m - 1;                                                     \
    for (int k = 0; k < m; k += 16) {                                   \
      half2v r_[8];                                                     \
      _Pragma("unroll")                                                 \
      for (int q = 0; q < 8; ++q) {                                     \
        int kk = k + 2 * q + eo; kk = (kk < cl) ? kk : cl;              \
        r_[q] = ROWS2[(size_t)__shfl(a, kk) * 32 + c];                  \
      }                                                                 \
      half2v b2 = hz;                                                   \
      _Pragma("unroll")                                                 \
      for (int q = 0; q < 8; ++q) {                                     \
        bool ok = (k + 2 * q + eo) < m;                                 \
        PKBODY                                                          \
      }                                                                 \
      AX += (float)b2.x; AY += (float)b2.y;                             \
    }                                                                   \
  }

#define GATHER_PAIR(ROWS2, B0v, E0v, B1v, E1v, PK0, PK1)                \
  {                                                                     \
    int mA = (E0v) - (B0v), mB = (E1v) - (B1v);                         \
    int aA = (lane < mA) ? adj[(B0v) + lane] : 0;                       \
    int aB = (lane < mB) ? adj[(B1v) + lane] : 0;                       \
    if (mA > 64) mA = 64;                                               \
    if (mB > 64) mB = 64;                                               \
    int clA = (mA > 0) ? mA - 1 : 0;                                    \
    int clB = (mB > 0) ? mB - 1 : 0;                                    \
    int mm = (mA > mB) ? mA : mB;                                       \
    for (int k = 0; k < mm; k += 16) {                                  \
      half2v r0_[8], r1_[8];                                            \
      _Pragma("unroll")                                                 \
      for (int q = 0; q < 8; ++q) {                                     \
        int kk = k + 2 * q + eo; int kc = (kk < clA) ? kk : clA;        \
        r0_[q] = ROWS2[(size_t)__shfl(aA, kc) * 32 + c];                \
      }                                                                 \
      _Pragma("unroll")                                                 \
      for (int q = 0; q < 8; ++q) {                                     \
        int kk = k + 2 * q + eo; int kc = (kk < clB) ? kk : clB;        \
        r1_[q] = ROWS2[(size_t)__shfl(aB, kc) * 32 + c];                \
      }                                                                 \
      half2v b20 = hz, b21 = hz;                                        \
      _Pragma("unroll")                                                 \
      for (int q = 0; q < 8; ++q) { bool ok = (k + 2 * q + eo) < mA; PK0 } \
      _Pragma("unroll")                                                 \
      for (int q = 0; q < 8; ++q) { bool ok = (k + 2 * q + eo) < mB; PK1 } \
      ax0 += (float)b20.x; ay0 += (float)b20.y;                         \
      ax1 += (float)b21.x; ay1 += (float)b21.y;                         \
    }                                                                   \
  }

// ---------------------------------------------------------------------------
// conv1 gather, 2 nodes per wave (paired, interleaved loads).  [R19-proven]
// ---------------------------------------------------------------------------
__global__ __launch_bounds__(256) void k_gcn1_gather(const int* __restrict__ offb,
                                                     const int* __restrict__ offe,
                                                     const int* __restrict__ adj,
                                                     const __half* __restrict__ xw1p,
                                                     const float* __restrict__ dinv,
                                                     const float* __restrict__ conv1_b,
                                                     const float* __restrict__ sv,
                                                     float* __restrict__ tp) {
  int w = blockIdx.x * 4 + (threadIdx.x >> 6);
  int i0 = 2 * w, i1 = 2 * w + 1;
  if (i0 >= NN) return;
  int lane = threadIdx.x & 63;
  int c = lane & 31, eo = lane >> 5;
  const half2v hz = {(_Float16)0.f, (_Float16)0.f};
  const half2v* X2 = (const half2v*)xw1p;
  int B0 = offb[i0], E0 = offe[i0];
  int B1 = offb[i1], E1 = offe[i1];
  float ax0 = 0.f, ay0 = 0.f, ax1 = 0.f, ay1 = 0.f;
  GATHER_PAIR(X2, B0, E0, B1, E1,
              { b20 += ok ? r0_[q] : hz; },
              { b21 += ok ? r1_[q] : hz; })
  if (E0 - B0 > 64) GATHER_ONE(X2, B0 + 64, E0, ax0, ay0, { b2 += ok ? r_[q] : hz; })
  if (E1 - B1 > 64) GATHER_ONE(X2, B1 + 64, E1, ax1, ay1, { b2 += ok ? r_[q] : hz; })
  ax0 += __shfl_xor(ax0, 32); ay0 += __shfl_xor(ay0, 32);
  ax1 += __shfl_xor(ax1, 32); ay1 += __shfl_xor(ay1, 32);
  float cb0 = conv1_b[2 * c], cb1 = conv1_b[2 * c + 1];
  float u0 = sv[2 * c], u1 = sv[2 * c + 1];
  {
    float di = dinv[i0];
    half2v self2 = X2[(size_t)i0 * 32 + c];
    float r0 = fmaxf(fmaf(ax0 + (float)self2.x, di, cb0), 0.f);
    float r1 = fmaxf(fmaf(ay0 + (float)self2.y, di, cb1), 0.f);
    float p = r0 * u0 + r1 * u1;
    if (eo) p = 0.f;
    p = waveReduceSum(p);
    if (lane == 0) tp[i0] = p * di;
  }
  {
    float di = dinv[i1];
    half2v self2 = X2[(size_t)i1 * 32 + c];
    float r0 = fmaxf(fmaf(ax1 + (float)self2.x, di, cb0), 0.f);
    float r1 = fmaxf(fmaf(ay1 + (float)self2.y, di, cb1), 0.f);
    float p = r0 * u0 + r1 * u1;
    if (eo) p = 0.f;
    p = waveReduceSum(p);
    if (lane == 0) tp[i1] = p * di;
  }
}

// ---------------------------------------------------------------------------
// Xe gather + batched matvec. 4 hyperedges/wave (2 pairs), grid 3125. [R19]
// ---------------------------------------------------------------------------
__global__ __launch_bounds__(256) void k_xe_gather(const int* __restrict__ offb,
                                                   const int* __restrict__ offe,
                                                   const int* __restrict__ adj,
                                                   const __half* __restrict__ C,
                                                   const int* __restrict__ W2P,
                                                   const float* __restrict__ b2bias,
                                                   __half* __restrict__ B) {
  __shared__ float hp[4][4][64];
  int lane = threadIdx.x & 63, wv = threadIdx.x >> 6;
  int c = lane & 31, eo = lane >> 5;
  const half2v hz = {(_Float16)0.f, (_Float16)0.f};
  const half2v* C2 = (const half2v*)C;
  int base = (blockIdx.x * 4 + wv) * 4;
  if (base >= NH) return;
  for (int np = 0; np < 2; ++np) {
    int e0 = base + 2 * np, e1 = e0 + 1;
    int B0 = offb[NN + e0], E0 = offe[NN + e0];
    int B1 = offb[NN + e1], E1 = offe[NN + e1];
    float ax0 = 0.f, ay0 = 0.f, ax1 = 0.f, ay1 = 0.f;
    GATHER_PAIR(C2, B0, E0, B1, E1,
                { b20 += ok ? r0_[q] : hz; },
                { b21 += ok ? r1_[q] : hz; })
    if (E0 - B0 > 64) GATHER_ONE(C2, B0 + 64, E0, ax0, ay0, { b2 += ok ? r_[q] : hz; })
    if (E1 - B1 > 64) GATHER_ONE(C2, B1 + 64, E1, ax1, ay1, { b2 += ok ? r_[q] : hz; })
    ax0 += __shfl_xor(ax0, 32); ay0 += __shfl_xor(ay0, 32);
    ax1 += __shfl_xor(ax1, 32); ay1 += __shfl_xor(ay1, 32);
    if (!eo) {
      float sc0 = 1.0f / fmaxf((float)(E0 - B0), 1.f);
      float sc1 = 1.0f / fmaxf((float)(E1 - B1), 1.f);
      hp[wv][2 * np][2 * c] = ax0 * sc0;
      hp[wv][2 * np][2 * c + 1] = ay0 * sc0;
      hp[wv][2 * np + 1][2 * c] = ax1 * sc1;
      hp[wv][2 * np + 1][2 * c + 1] = ay1 * sc1;
    }
  }
  __builtin_amdgcn_wave_barrier();
  int l2 = lane & 31;
  int hvp[4];
#pragma unroll
  for (int n = 0; n < 4; ++n) {
    half2v p;
    p.x = (_Float16)hp[wv][n][2 * l2];
    p.y = (_Float16)hp[wv][n][2 * l2 + 1];
    hvp[n] = __builtin_bit_cast(int, p);
  }
  float bb = b2bias[lane];
  float acc[4];
#pragma unroll
  for (int n = 0; n < 4; ++n) acc[n] = bb;
  for (int kk = 0; kk < 32; ++kk) {
    half2v wp = __builtin_bit_cast(half2v, W2P[kk * 64 + lane]);
#pragma unroll
    for (int n = 0; n < 4; ++n) {
      half2v hb = __builtin_bit_cast(half2v, __builtin_amdgcn_readlane(hvp[n], kk));
      acc[n] = fdot2f(hb, wp, acc[n]);
    }
  }
#pragma unroll
  for (int n = 0; n < 4; ++n)
    B[(size_t)(base + n) * 64 + lane] = (__half)acc[n];
}

// ---------------------------------------------------------------------------
// Final fused kernel. 8 nodes/wave SEQUENTIAL (R18-proven: VGPR 36, occ 60%).
// phase A (per node): packed xv-gather -> hpre in LDS; gcn2 scalar gather.
// phase B: fdot2 matvec with packed fp16 Wu; out = relu(hfin).w2v + scalar.
// ---------------------------------------------------------------------------
__global__ __launch_bounds__(256) void k_final(const int* __restrict__ offb,
                                               const int* __restrict__ offe,
                                               const int* __restrict__ adj,
                                               const __half* __restrict__ A,
                                               const __half* __restrict__ B,
                                               const __half* __restrict__ h,
                                               const float* __restrict__ tp,
                                               const float* __restrict__ dinv,
                                               const int* __restrict__ WUP,
                                               const float* __restrict__ bu,
                                               const float* __restrict__ sv,
                                               float* __restrict__ out) {
  __shared__ float hp[4][8][64];
  __shared__ float sarr[4][8];
  int lane = threadIdx.x & 63, wv = threadIdx.x >> 6;
  int c = lane & 31, eo = lane >> 5;
  const half2v hz = {(_Float16)0.f, (_Float16)0.f};
  const half2v* A2 = (const half2v*)A;
  const half2v* B2 = (const half2v*)B;
  const half2v* H2 = (const half2v*)h;
  int base = (blockIdx.x * 4 + wv) * 8;
  if (base >= NN) return;
  int ncnt = NN - base; if (ncnt > 8) ncnt = 8;
  float c_all = sv[128];
  for (int n = 0; n < ncnt; ++n) {
    int i = base + n;
    half2v av2 = A2[(size_t)i * 32 + c];
    int beg = offb[NN + NH + i], end = offe[NN + NH + i];
    float ax = 0.f, ay = 0.f;
    GATHER_ONE(B2, beg, end, ax, ay, {
      half2v s = av2 + r_[q];
      s = __builtin_elementwise_max(s, hz);
      b2 += ok ? s : hz;
    })
    ax += __shfl_xor(ax, 32);
    ay += __shfl_xor(ay, 32);
    if (!eo) {
      float sc = 0.5f / fmaxf((float)(end - beg), 1.f);
      half2v h2 = H2[(size_t)i * 32 + c];
      hp[wv][n][2 * c] = ax * sc + 0.5f * (float)h2.x;
      hp[wv][n][2 * c + 1] = ay * sc + 0.5f * (float)h2.y;
    }
    // gcn2 scalar gather over dst-CSR (all 64 lanes)
    float di = dinv[i];
    int db = offb[i], de = offe[i];
    float g = 0.f;
    for (int j = db + lane; j < de; j += 64) g += tp[adj[j]];
    float gr = waveReduceSum(g);
    if (lane == 0) sarr[wv][n] = gr * di + tp[i] * di + c_all;
  }
  __builtin_amdgcn_wave_barrier();
  int l2 = lane & 31;
  int hvp[8];
#pragma unroll
  for (int n = 0; n < 8; ++n) {
    half2v p;
    p.x = (_Float16)hp[wv][n][2 * l2];
    p.y = (_Float16)hp[wv][n][2 * l2 + 1];
    hvp[n] = __builtin_bit_cast(int, p);
  }
  float bb = bu[lane];
  float w2v = sv[64 + lane];
  float acc[8];
#pragma unroll
  for (int n = 0; n < 8; ++n) acc[n] = bb;
  for (int kk = 0; kk < 32; ++kk) {
    half2v wp = __builtin_bit_cast(half2v, WUP[kk * 64 + lane]);
#pragma unroll
    for (int n = 0; n < 8; ++n) {
      half2v hb = __builtin_bit_cast(half2v, __builtin_amdgcn_readlane(hvp[n], kk));
      acc[n] = fdot2f(hb, wp, acc[n]);
    }
  }
#pragma unroll
  for (int n = 0; n < 8; ++n) {
    if (n < ncnt) {
      float part = fmaxf(acc[n], 0.f) * w2v;
      float tot = waveReduceSum(part);
      if (lane == 0) out[base + n] = tot + sarr[wv][n];
    }
  }
}

// ---------------------------------------------------------------------------
extern "C" void kernel_launch(void* const* d_in, const int* in_sizes, int n_in,
                              void* d_out, int out_size, void* d_ws, size_t ws_size,
                              hipStream_t stream) {
  (void)in_sizes; (void)n_in; (void)out_size; (void)ws_size;
  const float* x       = (const float*)d_in[0];
  const int*   ei      = (const int*)d_in[1];
  const int*   hv      = (const int*)d_in[2];
  const int*   he      = (const int*)d_in[3];
  const float* conv1_W = (const float*)d_in[5];
  const float* conv1_b = (const float*)d_in[6];
  const float* conv2_W = (const float*)d_in[7];
  const float* conv2_b = (const float*)d_in[8];
  const float* lin_W   = (const float*)d_in[9];
  const float* lin_b   = (const float*)d_in[10];
  const float* W1      = (const float*)d_in[11];
  const float* b1      = (const float*)d_in[12];
  const float* W2      = (const float*)d_in[13];
  const float* b2      = (const float*)d_in[14];
  const float* Wu      = (const float*)d_in[15];
  const float* bu      = (const float*)d_in[16];
  const float* cls_W   = (const float*)d_in[17];
  const float* cls_b   = (const float*)d_in[18];
  const float* lp_W    = (const float*)d_in[19];
  const float* lp_b    = (const float*)d_in[20];
  const float* head_W  = (const float*)d_in[21];
  const float* head_b  = (const float*)d_in[22];
  const int* src = ei;
  const int* dst = ei + NE;
  float* out = (float*)d_out;

  // workspace layout
  __half* H16  = (__half*)d_ws;                         // NN*64 fp16  h
  __half* PH   = H16 + (size_t)NN * 64;                 // NN*64 fp16  xw1' then C
  __half* QH   = PH + (size_t)NN * 64;                  // NN*64 fp16  A
  __half* XEH  = QH + (size_t)NN * 64;                  // NH*64 fp16  B
  float* DINV  = (float*)(XEH + (size_t)NH * 64);       // NN
  float* TP    = DINV + NN;                 // NN   t' = t*dinv
  float* SV    = TP + NN;                   // 192
  int* PK      = (int*)(SV + 192);          // 16384 packed fp16x2 weight tables
  int* WUP     = PK;                        //  [0,2048)
  int* W2P     = PK + 2048;                 //  [2048,4096)
  int* C1P     = PK + 4096;                 //  [4096,8192)
  int* LWP     = PK + 8192;                 //  [8192,12288)
  int* W1P     = PK + 12288;                //  [12288,14336)
  int* W2AP    = PK + 14336;                //  [14336,16384)
  int* GCUR    = PK + 16384;                // NBUK
  int* OFFB    = GCUR + NBUK;               // NS
  int* OFFE    = OFFB + NS;                 // NS
  int* ADJ     = OFFE + NS;                 // NBUK*P2CAP (24 MB)

  hipMemsetAsync(GCUR, 0, NBUK * 4, stream);

  k_vecs<<<1, 64, 0, stream>>>(conv2_W, conv2_b, cls_W, cls_b, lp_W, lp_b, head_W, head_b, SV);
  k_pack<<<64, 256, 0, stream>>>(Wu, W2, conv1_W, lin_W, W1, PK);

  // CSR build (strided buckets; no global scan pass)
  k_phase1<<<NWG1, 1024, 0, stream>>>(src, dst, he, hv, GCUR, ADJ);
  k_phase2<<<NBUK, 256, 0, stream>>>(GCUR, ADJ, OFFB, OFFE);
  k_dinv<<<(NN + 255) / 256, 256, 0, stream>>>(OFFB, OFFE, DINV);

  // dense: xw1' and h in ONE pass over x
  k_gemm128_dual<<<2048, 256, 0, stream>>>(x, C1P, LWP, lin_b, DINV, PH, H16, NN);

  // GCN branch collapsed to t' (2 nodes/wave -> 12500 blocks)
  k_gcn1_gather<<<12500, 256, 0, stream>>>(OFFB, OFFE, ADJ, PH, DINV, conv1_b, SV, TP);

  // hyper branch dense parts fused: C = h@W1+b1 (PH), A = h@W2[:64] (QH)
  k_gemm_dual<<<2048, 256, 0, stream>>>(H16, W1P, b1, W2AP, PH, QH, NN);

  // 4 hyperedges per wave -> 3125 blocks
  k_xe_gather<<<3125, 256, 0, stream>>>(OFFB, OFFE, ADJ, PH, W2P, b2, XEH);

  // 8 nodes per wave -> 3125 blocks
  k_final<<<3125, 256, 0, stream>>>(OFFB, OFFE, ADJ, QH, XEH, H16, TP, DINV, WUP, bu, SV, out);
}